// Round 4
// baseline (956.916 us; speedup 1.0000x reference)
//
#include <hip/hip_runtime.h>
#include <hip/hip_bf16.h>
#include <stdint.h>

#define B_  32
#define L_  256
#define T_  32
#define D_  300
#define H_  256
#define G3  768   // 3*H

typedef _Float16 half2_t __attribute__((ext_vector_type(2)));

__device__ __forceinline__ float fdot2(uint32_t w, uint32_t h, float acc) {
#if defined(__has_builtin) && __has_builtin(__builtin_amdgcn_fdot2)
  return __builtin_amdgcn_fdot2(__builtin_bit_cast(half2_t, w),
                                __builtin_bit_cast(half2_t, h), acc, false);
#else
  half2_t a = __builtin_bit_cast(half2_t, w);
  half2_t b = __builtin_bit_cast(half2_t, h);
  return acc + (float)a[0] * (float)b[0] + (float)a[1] * (float)b[1];
#endif
}

__device__ __forceinline__ uint32_t pack2(float x, float y) {
  half2_t h;
  h[0] = (_Float16)x;
  h[1] = (_Float16)y;
  return __builtin_bit_cast(uint32_t, h);
}

__device__ __forceinline__ float rcp_f(float x) { return __builtin_amdgcn_rcpf(x); }
__device__ __forceinline__ float sigmoid_f(float x) { return rcp_f(1.0f + __expf(-x)); }
__device__ __forceinline__ float tanh_f(float x) {
  float e2 = __expf(2.0f * x);
  return 1.0f - 2.0f * rcp_f(e2 + 1.0f);
}

// ---- pack Whh [768][256] f32 -> wT2 [128][768] f16x2 (pairs along K) ----
__global__ void pack_whh(const float* __restrict__ Whh, uint32_t* __restrict__ wT2) {
  const int idx = blockIdx.x * 256 + threadIdx.x;   // 0..98303
  const int row = idx % G3;
  const int kk  = idx / G3;
  wT2[idx] = pack2(Whh[row * H_ + 2 * kk], Whh[row * H_ + 2 * kk + 1]);
}

// ---- dtok[i] = Xin[b*L + Xindex[i]] ----
__global__ void gather_dtok(const int* __restrict__ Xin, const int* __restrict__ Xindex,
                            int* __restrict__ dtok) {
  const int i = blockIdx.x * 256 + threadIdx.x;   // 0..1023
  const int b = i >> 5;                           // /T_
  dtok[i] = Xin[b * L_ + Xindex[i]];
}

// ---- generic C = A @ W^T (+bias), A rows optionally gathered; out optionally
//      stored transposed per 256-row batch: C[b][n][l], m = b*256+l ----
template<bool GATHER, bool TRANSP, bool BIAS>
__global__ __launch_bounds__(256)
void gemm_awt(const float* __restrict__ A, const int* __restrict__ rowidx,
              const float* __restrict__ W, const float* __restrict__ bias,
              float* __restrict__ C, int M, int N, int K) {
  __shared__ float As[16][68];
  __shared__ float Ws[16][68];
  const int tid = threadIdx.x;
  const int bm = blockIdx.x, bn = blockIdx.y;
  const int ty = tid >> 4, tx = tid & 15;
  const int r  = tid >> 2;
  const int c4 = (tid & 3) << 2;
  const long arow = (long)bm * 64 + r;
  const float* Arow = GATHER ? (A + (long)rowidx[arow] * K) : (A + arow * (long)K);
  const float* Wrow = W + ((long)bn * 64 + r) * K;
  float acc[4][4] = {};
  for (int k0 = 0; k0 < K; k0 += 16) {
    float4 av, wv;
    if (k0 + c4 + 3 < K) {
      av = *(const float4*)(Arow + k0 + c4);
      wv = *(const float4*)(Wrow + k0 + c4);
    } else {
      float ta[4] = {0, 0, 0, 0}, tw[4] = {0, 0, 0, 0};
      for (int u = 0; u < 4; ++u)
        if (k0 + c4 + u < K) { ta[u] = Arow[k0 + c4 + u]; tw[u] = Wrow[k0 + c4 + u]; }
      av.x = ta[0]; av.y = ta[1]; av.z = ta[2]; av.w = ta[3];
      wv.x = tw[0]; wv.y = tw[1]; wv.z = tw[2]; wv.w = tw[3];
    }
    __syncthreads();
    As[c4 + 0][r] = av.x; As[c4 + 1][r] = av.y; As[c4 + 2][r] = av.z; As[c4 + 3][r] = av.w;
    Ws[c4 + 0][r] = wv.x; Ws[c4 + 1][r] = wv.y; Ws[c4 + 2][r] = wv.z; Ws[c4 + 3][r] = wv.w;
    __syncthreads();
#pragma unroll
    for (int k = 0; k < 16; ++k) {
      const float4 a4 = *(const float4*)&As[k][ty << 2];
      const float4 b4 = *(const float4*)&Ws[k][tx << 2];
      acc[0][0] = fmaf(a4.x, b4.x, acc[0][0]);
      acc[0][1] = fmaf(a4.x, b4.y, acc[0][1]);
      acc[0][2] = fmaf(a4.x, b4.z, acc[0][2]);
      acc[0][3] = fmaf(a4.x, b4.w, acc[0][3]);
      acc[1][0] = fmaf(a4.y, b4.x, acc[1][0]);
      acc[1][1] = fmaf(a4.y, b4.y, acc[1][1]);
      acc[1][2] = fmaf(a4.y, b4.z, acc[1][2]);
      acc[1][3] = fmaf(a4.y, b4.w, acc[1][3]);
      acc[2][0] = fmaf(a4.z, b4.x, acc[2][0]);
      acc[2][1] = fmaf(a4.z, b4.y, acc[2][1]);
      acc[2][2] = fmaf(a4.z, b4.z, acc[2][2]);
      acc[2][3] = fmaf(a4.z, b4.w, acc[2][3]);
      acc[3][0] = fmaf(a4.w, b4.x, acc[3][0]);
      acc[3][1] = fmaf(a4.w, b4.y, acc[3][1]);
      acc[3][2] = fmaf(a4.w, b4.z, acc[3][2]);
      acc[3][3] = fmaf(a4.w, b4.w, acc[3][3]);
    }
  }
#pragma unroll
  for (int i = 0; i < 4; ++i) {
    const int m = bm * 64 + (ty << 2) + i;
#pragma unroll
    for (int j = 0; j < 4; ++j) {
      const int n = bn * 64 + (tx << 2) + j;
      float v = acc[i][j];
      if (BIAS) v += bias[n];
      if (TRANSP) C[(((long)(m >> 8) * N + n) << 8) + (m & 255)] = v;
      else        C[(long)m * N + n] = v;
    }
  }
}

// ============ sequential GRU, 512 threads, K split 2-way ============
// Thread (j, half) owns rows {j, H+j, 2H+j} restricted to K-pairs
// [half*64, half*64+64). Weights in 48 NAMED uint4 registers, pinned with
// opaque asm so the scheduler cannot sink/rematerialize the loads into the
// t-loop (that sinking is what kept rounds 2-3 L2-stream-bound at ~57 B/cy).

__device__ __forceinline__ uint4 ld4w(const uint32_t* __restrict__ b, int off, int q) {
  uint4 v;
  v.x = b[(4 * q + 0) * G3 + off];
  v.y = b[(4 * q + 1) * G3 + off];
  v.z = b[(4 * q + 2) * G3 + off];
  v.w = b[(4 * q + 3) * G3 + off];
  return v;
}

#define WDECL(p) uint4 p##0, p##1, p##2, p##3, p##4, p##5, p##6, p##7, \
                       p##8, p##9, p##10, p##11, p##12, p##13, p##14, p##15
#define WLOAD(p, base, off) \
  p##0  = ld4w(base, off, 0);  p##1  = ld4w(base, off, 1);  \
  p##2  = ld4w(base, off, 2);  p##3  = ld4w(base, off, 3);  \
  p##4  = ld4w(base, off, 4);  p##5  = ld4w(base, off, 5);  \
  p##6  = ld4w(base, off, 6);  p##7  = ld4w(base, off, 7);  \
  p##8  = ld4w(base, off, 8);  p##9  = ld4w(base, off, 9);  \
  p##10 = ld4w(base, off, 10); p##11 = ld4w(base, off, 11); \
  p##12 = ld4w(base, off, 12); p##13 = ld4w(base, off, 13); \
  p##14 = ld4w(base, off, 14); p##15 = ld4w(base, off, 15)
#define PIN4(v) asm volatile("" : "+v"(v.x), "+v"(v.y), "+v"(v.z), "+v"(v.w))
#define WPIN(p) \
  PIN4(p##0);  PIN4(p##1);  PIN4(p##2);  PIN4(p##3);  \
  PIN4(p##4);  PIN4(p##5);  PIN4(p##6);  PIN4(p##7);  \
  PIN4(p##8);  PIN4(p##9);  PIN4(p##10); PIN4(p##11); \
  PIN4(p##12); PIN4(p##13); PIN4(p##14); PIN4(p##15)

#define STEP_Q(q) { \
  const uint4 hp = h2v[q]; \
  ar = fdot2(wr##q.x, hp.x, ar); az = fdot2(wz##q.x, hp.x, az); an = fdot2(wn##q.x, hp.x, an); \
  ar = fdot2(wr##q.y, hp.y, ar); az = fdot2(wz##q.y, hp.y, az); an = fdot2(wn##q.y, hp.y, an); \
  ar = fdot2(wr##q.z, hp.z, ar); az = fdot2(wz##q.z, hp.z, az); an = fdot2(wn##q.z, hp.z, an); \
  ar = fdot2(wr##q.w, hp.w, ar); az = fdot2(wz##q.w, hp.w, az); an = fdot2(wn##q.w, hp.w, an); }

__global__ __attribute__((amdgpu_flat_work_group_size(512, 512), amdgpu_waves_per_eu(2, 2)))
void gru_seq(const float* __restrict__ xg, const uint32_t* __restrict__ wT2,
             const float* __restrict__ bhh, const float* __restrict__ h0,
             float* __restrict__ hout, float* __restrict__ hlast, int S) {
  const int b = blockIdx.x;
  const int tid = threadIdx.x;
  const int j = tid & 255;
  const int half = tid >> 8;
  const uint32_t* wbase = wT2 + (size_t)half * 64 * G3;
  WDECL(wr); WDECL(wz); WDECL(wn);
  WLOAD(wr, wbase, j);
  WLOAD(wz, wbase, H_ + j);
  WLOAD(wn, wbase, 2 * H_ + j);
  WPIN(wr); WPIN(wz); WPIN(wn);
  __shared__ __align__(16) uint32_t h2[H_ / 2];
  __shared__ float pr[H_], pz[H_], pn[H_];
  const float bhr = bhh[j], bhz = bhh[H_ + j], bhn = bhh[2 * H_ + j];
  const float* xgb = xg + (long)b * S * G3;
  float h = 0.0f;
  float xr = 0.0f, xz = 0.0f, xn = 0.0f;
  if (half == 0) {
    h = h0 ? h0[b * H_ + j] : 0.0f;
    ((_Float16*)h2)[j] = (_Float16)h;
    xr = xgb[j]; xz = xgb[H_ + j]; xn = xgb[2 * H_ + j];
  }
  __syncthreads();
  for (int t = 0; t < S; ++t) {
    float ar = 0.0f, az = 0.0f, an = 0.0f;
    const uint4* h2v = (const uint4*)h2 + half * 16;
    STEP_Q(0)  STEP_Q(1)  STEP_Q(2)  STEP_Q(3)
    STEP_Q(4)  STEP_Q(5)  STEP_Q(6)  STEP_Q(7)
    STEP_Q(8)  STEP_Q(9)  STEP_Q(10) STEP_Q(11)
    STEP_Q(12) STEP_Q(13) STEP_Q(14) STEP_Q(15)
    // prefetch next step's x while dots are in flight
    float nxr = 0.0f, nxz = 0.0f, nxn = 0.0f;
    if (half == 0 && t + 1 < S) {
      const float* xp = xgb + (long)(t + 1) * G3;
      nxr = xp[j]; nxz = xp[H_ + j]; nxn = xp[2 * H_ + j];
    }
    if (half == 1) { pr[j] = ar; pz[j] = az; pn[j] = an; }
    __syncthreads();
    if (half == 0) {
      ar += pr[j] + bhr;
      az += pz[j] + bhz;
      an += pn[j] + bhn;
      const float r = sigmoid_f(xr + ar);
      const float z = sigmoid_f(xz + az);
      const float n = tanh_f(xn + r * an);
      h = (1.0f - z) * n + z * h;
      hout[((long)b * S + t) * H_ + j] = h;
      ((_Float16*)h2)[j] = (_Float16)h;
    }
    xr = nxr; xz = nxz; xn = nxn;
    __syncthreads();
  }
  if (half == 0 && hlast) hlast[b * H_ + j] = h;
}

// ---- fused pointer layer + masked log-softmax + loss accumulation ----
// grid (T, B), 256 threads = one per l. WEt is [b][h][l] (transposed).
__global__ __launch_bounds__(256)
void pointer_loss(const float* __restrict__ WEt, const float* __restrict__ WD,
                  const float* __restrict__ Vv,
                  const int* __restrict__ Xindex, const int* __restrict__ Yindex,
                  const int* __restrict__ lens, float* __restrict__ out) {
  const int t = blockIdx.x, b = blockIdx.y;
  const int l = threadIdx.x;
  __shared__ float wd_s[H_], vv_s[H_];
  __shared__ float rbuf[4], sbuf[4], vy_s;
  const int bt = b * T_ + t;
  wd_s[l] = WD[(long)bt * H_ + l];
  vv_s[l] = Vv[l] * 1.0507009873554805f;   // fold selu scale of inner selu into Vv
  __syncthreads();
  const float* wet = WEt + (long)b * H_ * L_;
  const float alpha = 1.6732632423543772f;
  float acc = 0.0f;
#pragma unroll 4
  for (int hh = 0; hh < H_; ++hh) {
    const float xsum = wet[hh * L_ + l] + wd_s[hh];
    const float sneg = alpha * (__expf(xsum) - 1.0f);
    const float s = xsum > 0.0f ? xsum : sneg;
    acc = fmaf(s, vv_s[hh], acc);
  }
  float v;
  {
    const float sneg = alpha * (__expf(acc) - 1.0f);
    v = 1.0507009873554805f * (acc > 0.0f ? acc : sneg);
  }
  const int start = Xindex[bt];
  const int len = lens[b];
  const bool valid = (l >= start) && (l < len);
  const int y = Yindex[bt];
  if (l == y) vy_s = v;
  float m = valid ? v : -INFINITY;
  for (int off = 32; off > 0; off >>= 1) m = fmaxf(m, __shfl_xor(m, off, 64));
  const int wid = l >> 6, lane = l & 63;
  if (lane == 0) rbuf[wid] = m;
  __syncthreads();
  const float mx = fmaxf(fmaxf(rbuf[0], rbuf[1]), fmaxf(rbuf[2], rbuf[3]));
  float e = valid ? __expf(v - mx) : 0.0f;
  for (int off = 32; off > 0; off >>= 1) e += __shfl_xor(e, off, 64);
  if (lane == 0) sbuf[wid] = e;
  __syncthreads();
  if (l == 0) {
    const float sum = sbuf[0] + sbuf[1] + sbuf[2] + sbuf[3];
    atomicAdd(out, (mx + __logf(sum) - vy_s) * (1.0f / (B_ * T_)));
  }
}

extern "C" void kernel_launch(void* const* d_in, const int* in_sizes, int n_in,
                              void* d_out, int out_size, void* d_ws, size_t ws_size,
                              hipStream_t stream) {
  (void)in_sizes; (void)n_in; (void)out_size; (void)ws_size;
  const int*   Xin    = (const int*)d_in[0];
  const int*   Xindex = (const int*)d_in[1];
  const int*   Yindex = (const int*)d_in[2];
  const int*   lens   = (const int*)d_in[3];
  const float* emb    = (const float*)d_in[4];
  const float* Wih_e  = (const float*)d_in[5];
  const float* Whh_e  = (const float*)d_in[6];
  const float* bih_e  = (const float*)d_in[7];
  const float* bhh_e  = (const float*)d_in[8];
  const float* Wih_d  = (const float*)d_in[9];
  const float* Whh_d  = (const float*)d_in[10];
  const float* bih_d  = (const float*)d_in[11];
  const float* bhh_d  = (const float*)d_in[12];
  const float* W1     = (const float*)d_in[13];
  const float* W2     = (const float*)d_in[14];
  const float* Vv     = (const float*)d_in[15];

  char* p = (char*)d_ws;
  auto take = [&](size_t bytes) { void* q = (void*)p; p += (bytes + 255) & ~(size_t)255; return q; };
  uint32_t* wT2_e = (uint32_t*)take((size_t)98304 * 4);
  uint32_t* wT2_d = (uint32_t*)take((size_t)98304 * 4);
  float* xg_e  = (float*)take((size_t)8192 * 768 * 4);
  float* xg_d  = (float*)take((size_t)1024 * 768 * 4);
  float* hn    = (float*)take((size_t)8192 * 256 * 4);
  float* hend  = (float*)take((size_t)8192 * 4);
  float* hl_d  = (float*)take((size_t)8192 * 4);
  float* doutb = (float*)take((size_t)1024 * 256 * 4);
  float* WEt   = (float*)take((size_t)8192 * 256 * 4);
  float* WDb   = (float*)take((size_t)1024 * 256 * 4);
  int*   dtok  = (int*)take((size_t)1024 * 4);

  hipMemsetAsync(d_out, 0, sizeof(float), stream);

  hipLaunchKernelGGL(pack_whh, dim3(384), dim3(256), 0, stream, Whh_e, wT2_e);
  hipLaunchKernelGGL(pack_whh, dim3(384), dim3(256), 0, stream, Whh_d, wT2_d);
  hipLaunchKernelGGL(gather_dtok, dim3(4), dim3(256), 0, stream, Xin, Xindex, dtok);

  // xg_e = emb[Xin] @ Wih_e^T + bih_e   [8192 x 768], K=300
  hipLaunchKernelGGL((gemm_awt<true, false, true>), dim3(128, 12), dim3(256), 0, stream,
                     emb, Xin, Wih_e, bih_e, xg_e, 8192, 768, 300);
  // xg_d = emb[dtok] @ Wih_d^T + bih_d  [1024 x 768], K=300
  hipLaunchKernelGGL((gemm_awt<true, false, true>), dim3(16, 12), dim3(256), 0, stream,
                     emb, dtok, Wih_d, bih_d, xg_d, 1024, 768, 300);

  // encoder GRU (h0 = 0), outputs hn [B,L,H] and hend [B,H]
  hipLaunchKernelGGL(gru_seq, dim3(32), dim3(512), 0, stream,
                     xg_e, wT2_e, bhh_e, (const float*)nullptr, hn, hend, L_);
  // decoder GRU (h0 = hend), outputs doutb [B,T,H]
  hipLaunchKernelGGL(gru_seq, dim3(32), dim3(512), 0, stream,
                     xg_d, wT2_d, bhh_d, hend, doutb, hl_d, T_);

  // WEt[b][k][l] = sum_h hn[b,l,h] * W1[k,h]   (transposed store)
  hipLaunchKernelGGL((gemm_awt<false, true, false>), dim3(128, 4), dim3(256), 0, stream,
                     hn, (const int*)nullptr, W1, (const float*)nullptr, WEt, 8192, 256, 256);
  // WD[b,t,k] = sum_h doutb[b,t,h] * W2[k,h]
  hipLaunchKernelGGL((gemm_awt<false, false, false>), dim3(16, 4), dim3(256), 0, stream,
                     doutb, (const int*)nullptr, W2, (const float*)nullptr, WDb, 1024, 256, 256);

  // fused pointer layer + loss
  hipLaunchKernelGGL(pointer_loss, dim3(T_, B_), dim3(256), 0, stream,
                     WEt, WDb, Vv, Xindex, Yindex, lens, (float*)d_out);
}

// Round 5
// 510.659 us; speedup vs baseline: 1.8739x; 1.8739x over previous
//
#include <hip/hip_runtime.h>
#include <hip/hip_bf16.h>
#include <stdint.h>

#define B_  32
#define L_  256
#define T_  32
#define D_  300
#define H_  256
#define G3  768   // 3*H

typedef _Float16 half2_t __attribute__((ext_vector_type(2)));

__device__ __forceinline__ float fdot2(uint32_t w, uint32_t h, float acc) {
#if defined(__has_builtin) && __has_builtin(__builtin_amdgcn_fdot2)
  return __builtin_amdgcn_fdot2(__builtin_bit_cast(half2_t, w),
                                __builtin_bit_cast(half2_t, h), acc, false);
#else
  half2_t a = __builtin_bit_cast(half2_t, w);
  half2_t b = __builtin_bit_cast(half2_t, h);
  return acc + (float)a[0] * (float)b[0] + (float)a[1] * (float)b[1];
#endif
}

__device__ __forceinline__ uint32_t pack2(float x, float y) {
  half2_t h;
  h[0] = (_Float16)x;
  h[1] = (_Float16)y;
  return __builtin_bit_cast(uint32_t, h);
}

__device__ __forceinline__ float rcp_f(float x) { return __builtin_amdgcn_rcpf(x); }
__device__ __forceinline__ float sigmoid_f(float x) { return rcp_f(1.0f + __expf(-x)); }
__device__ __forceinline__ float tanh_f(float x) {
  float e2 = __expf(2.0f * x);
  return 1.0f - 2.0f * rcp_f(e2 + 1.0f);
}

// ---- pack Whh [768][256] f32 -> wT2 [128][768] f16x2 (pairs along K) ----
__global__ void pack_whh(const float* __restrict__ Whh, uint32_t* __restrict__ wT2) {
  const int idx = blockIdx.x * 256 + threadIdx.x;   // 0..98303
  const int row = idx % G3;
  const int kk  = idx / G3;
  wT2[idx] = pack2(Whh[row * H_ + 2 * kk], Whh[row * H_ + 2 * kk + 1]);
}

// ---- dtok[i] = Xin[b*L + Xindex[i]] ----
__global__ void gather_dtok(const int* __restrict__ Xin, const int* __restrict__ Xindex,
                            int* __restrict__ dtok) {
  const int i = blockIdx.x * 256 + threadIdx.x;   // 0..1023
  const int b = i >> 5;                           // /T_
  dtok[i] = Xin[b * L_ + Xindex[i]];
}

// ---- generic C = A @ W^T (+bias), A rows optionally gathered; out optionally
//      stored transposed per 256-row batch: C[b][n][l], m = b*256+l ----
template<bool GATHER, bool TRANSP, bool BIAS>
__global__ __launch_bounds__(256)
void gemm_awt(const float* __restrict__ A, const int* __restrict__ rowidx,
              const float* __restrict__ W, const float* __restrict__ bias,
              float* __restrict__ C, int M, int N, int K) {
  __shared__ float As[16][68];
  __shared__ float Ws[16][68];
  const int tid = threadIdx.x;
  const int bm = blockIdx.x, bn = blockIdx.y;
  const int ty = tid >> 4, tx = tid & 15;
  const int r  = tid >> 2;
  const int c4 = (tid & 3) << 2;
  const long arow = (long)bm * 64 + r;
  const float* Arow = GATHER ? (A + (long)rowidx[arow] * K) : (A + arow * (long)K);
  const float* Wrow = W + ((long)bn * 64 + r) * K;
  float acc[4][4] = {};
  for (int k0 = 0; k0 < K; k0 += 16) {
    float4 av, wv;
    if (k0 + c4 + 3 < K) {
      av = *(const float4*)(Arow + k0 + c4);
      wv = *(const float4*)(Wrow + k0 + c4);
    } else {
      float ta[4] = {0, 0, 0, 0}, tw[4] = {0, 0, 0, 0};
      for (int u = 0; u < 4; ++u)
        if (k0 + c4 + u < K) { ta[u] = Arow[k0 + c4 + u]; tw[u] = Wrow[k0 + c4 + u]; }
      av.x = ta[0]; av.y = ta[1]; av.z = ta[2]; av.w = ta[3];
      wv.x = tw[0]; wv.y = tw[1]; wv.z = tw[2]; wv.w = tw[3];
    }
    __syncthreads();
    As[c4 + 0][r] = av.x; As[c4 + 1][r] = av.y; As[c4 + 2][r] = av.z; As[c4 + 3][r] = av.w;
    Ws[c4 + 0][r] = wv.x; Ws[c4 + 1][r] = wv.y; Ws[c4 + 2][r] = wv.z; Ws[c4 + 3][r] = wv.w;
    __syncthreads();
#pragma unroll
    for (int k = 0; k < 16; ++k) {
      const float4 a4 = *(const float4*)&As[k][ty << 2];
      const float4 b4 = *(const float4*)&Ws[k][tx << 2];
      acc[0][0] = fmaf(a4.x, b4.x, acc[0][0]);
      acc[0][1] = fmaf(a4.x, b4.y, acc[0][1]);
      acc[0][2] = fmaf(a4.x, b4.z, acc[0][2]);
      acc[0][3] = fmaf(a4.x, b4.w, acc[0][3]);
      acc[1][0] = fmaf(a4.y, b4.x, acc[1][0]);
      acc[1][1] = fmaf(a4.y, b4.y, acc[1][1]);
      acc[1][2] = fmaf(a4.y, b4.z, acc[1][2]);
      acc[1][3] = fmaf(a4.y, b4.w, acc[1][3]);
      acc[2][0] = fmaf(a4.z, b4.x, acc[2][0]);
      acc[2][1] = fmaf(a4.z, b4.y, acc[2][1]);
      acc[2][2] = fmaf(a4.z, b4.z, acc[2][2]);
      acc[2][3] = fmaf(a4.z, b4.w, acc[2][3]);
      acc[3][0] = fmaf(a4.w, b4.x, acc[3][0]);
      acc[3][1] = fmaf(a4.w, b4.y, acc[3][1]);
      acc[3][2] = fmaf(a4.w, b4.z, acc[3][2]);
      acc[3][3] = fmaf(a4.w, b4.w, acc[3][3]);
    }
  }
#pragma unroll
  for (int i = 0; i < 4; ++i) {
    const int m = bm * 64 + (ty << 2) + i;
#pragma unroll
    for (int j = 0; j < 4; ++j) {
      const int n = bn * 64 + (tx << 2) + j;
      float v = acc[i][j];
      if (BIAS) v += bias[n];
      if (TRANSP) C[(((long)(m >> 8) * N + n) << 8) + (m & 255)] = v;
      else        C[(long)m * N + n] = v;
    }
  }
}

// ============ sequential GRU, 1024 threads, K split 4-way ============
// tid = q*256 + j. Thread owns rows {j, H+j, 2H+j}, K-pairs [q*32, q*32+32)
// = 96 weight dwords -> fits the 128-VGPR budget the compiler insists on
// (rounds 2-4: 192-dword versions spilled to scratch at the same ~57 B/cy
// L2 path as streaming). Wave = 64 consecutive j, same q => LDS h-reads are
// wave-uniform broadcasts. Partials reduced via LDS; gates on q==0 waves.

__device__ __forceinline__ uint4 ld4w(const uint32_t* __restrict__ b, int off, int c) {
  uint4 v;
  v.x = b[(4 * c + 0) * G3 + off];
  v.y = b[(4 * c + 1) * G3 + off];
  v.z = b[(4 * c + 2) * G3 + off];
  v.w = b[(4 * c + 3) * G3 + off];
  return v;
}

#define WDECL8(p) uint4 p##0, p##1, p##2, p##3, p##4, p##5, p##6, p##7
#define WLOAD8(p, base, off) \
  p##0 = ld4w(base, off, 0); p##1 = ld4w(base, off, 1); \
  p##2 = ld4w(base, off, 2); p##3 = ld4w(base, off, 3); \
  p##4 = ld4w(base, off, 4); p##5 = ld4w(base, off, 5); \
  p##6 = ld4w(base, off, 6); p##7 = ld4w(base, off, 7)
#define PIN4(v) asm volatile("" : "+v"(v.x), "+v"(v.y), "+v"(v.z), "+v"(v.w))
#define WPIN8(p) \
  PIN4(p##0); PIN4(p##1); PIN4(p##2); PIN4(p##3); \
  PIN4(p##4); PIN4(p##5); PIN4(p##6); PIN4(p##7)

#define STEP_I(i) { \
  const uint4 hp = hp8[i]; \
  ar = fdot2(wr##i.x, hp.x, ar); az = fdot2(wz##i.x, hp.x, az); an = fdot2(wn##i.x, hp.x, an); \
  ar = fdot2(wr##i.y, hp.y, ar); az = fdot2(wz##i.y, hp.y, az); an = fdot2(wn##i.y, hp.y, an); \
  ar = fdot2(wr##i.z, hp.z, ar); az = fdot2(wz##i.z, hp.z, az); an = fdot2(wn##i.z, hp.z, an); \
  ar = fdot2(wr##i.w, hp.w, ar); az = fdot2(wz##i.w, hp.w, az); an = fdot2(wn##i.w, hp.w, an); }

__global__ __launch_bounds__(1024)
void gru_seq(const float* __restrict__ xg, const uint32_t* __restrict__ wT2,
             const float* __restrict__ bhh, const float* __restrict__ h0,
             float* __restrict__ hout, float* __restrict__ hlast, int S) {
  const int b = blockIdx.x;
  const int tid = threadIdx.x;
  const int j = tid & 255;
  const int q = tid >> 8;
  const uint32_t* wbase = wT2 + (size_t)q * 32 * G3;  // kk base = q*32 pairs
  WDECL8(wr); WDECL8(wz); WDECL8(wn);
  WLOAD8(wr, wbase, j);
  WLOAD8(wz, wbase, H_ + j);
  WLOAD8(wn, wbase, 2 * H_ + j);
  WPIN8(wr); WPIN8(wz); WPIN8(wn);
  __shared__ __align__(16) uint32_t h2[H_ / 2];
  __shared__ float part[3][4][H_];   // [gate][q][j]; q=0 slice unused
  const float bhr = bhh[j], bhz = bhh[H_ + j], bhn = bhh[2 * H_ + j];
  const float* xgb = xg + (long)b * S * G3;
  float h = 0.0f;
  float xr = 0.0f, xz = 0.0f, xn = 0.0f;
  if (q == 0) {
    h = h0 ? h0[b * H_ + j] : 0.0f;
    ((_Float16*)h2)[j] = (_Float16)h;
    xr = xgb[j]; xz = xgb[H_ + j]; xn = xgb[2 * H_ + j];
  }
  __syncthreads();
  for (int t = 0; t < S; ++t) {
    float ar = 0.0f, az = 0.0f, an = 0.0f;
    const uint4* hp8 = (const uint4*)h2 + q * 8;
    STEP_I(0) STEP_I(1) STEP_I(2) STEP_I(3)
    STEP_I(4) STEP_I(5) STEP_I(6) STEP_I(7)
    if (q) { part[0][q][j] = ar; part[1][q][j] = az; part[2][q][j] = an; }
    // prefetch next step's x while barrier drains
    float nxr = 0.0f, nxz = 0.0f, nxn = 0.0f;
    if (q == 0 && t + 1 < S) {
      const float* xp = xgb + (long)(t + 1) * G3;
      nxr = xp[j]; nxz = xp[H_ + j]; nxn = xp[2 * H_ + j];
    }
    __syncthreads();
    if (q == 0) {
      ar += part[0][1][j] + part[0][2][j] + part[0][3][j] + bhr;
      az += part[1][1][j] + part[1][2][j] + part[1][3][j] + bhz;
      an += part[2][1][j] + part[2][2][j] + part[2][3][j] + bhn;
      const float r = sigmoid_f(xr + ar);
      const float z = sigmoid_f(xz + az);
      const float n = tanh_f(xn + r * an);
      h = (1.0f - z) * n + z * h;
      hout[((long)b * S + t) * H_ + j] = h;
      ((_Float16*)h2)[j] = (_Float16)h;
    }
    xr = nxr; xz = nxz; xn = nxn;
    __syncthreads();
  }
  if (q == 0 && hlast) hlast[b * H_ + j] = h;
}

// ---- fused pointer layer + masked log-softmax + loss accumulation ----
// grid (T, B), 256 threads = one per l. WEt is [b][h][l] (transposed).
__global__ __launch_bounds__(256)
void pointer_loss(const float* __restrict__ WEt, const float* __restrict__ WD,
                  const float* __restrict__ Vv,
                  const int* __restrict__ Xindex, const int* __restrict__ Yindex,
                  const int* __restrict__ lens, float* __restrict__ out) {
  const int t = blockIdx.x, b = blockIdx.y;
  const int l = threadIdx.x;
  __shared__ float wd_s[H_], vv_s[H_];
  __shared__ float rbuf[4], sbuf[4], vy_s;
  const int bt = b * T_ + t;
  wd_s[l] = WD[(long)bt * H_ + l];
  vv_s[l] = Vv[l] * 1.0507009873554805f;   // fold selu scale of inner selu into Vv
  __syncthreads();
  const float* wet = WEt + (long)b * H_ * L_;
  const float alpha = 1.6732632423543772f;
  float acc = 0.0f;
#pragma unroll 4
  for (int hh = 0; hh < H_; ++hh) {
    const float xsum = wet[hh * L_ + l] + wd_s[hh];
    const float sneg = alpha * (__expf(xsum) - 1.0f);
    const float s = xsum > 0.0f ? xsum : sneg;
    acc = fmaf(s, vv_s[hh], acc);
  }
  float v;
  {
    const float sneg = alpha * (__expf(acc) - 1.0f);
    v = 1.0507009873554805f * (acc > 0.0f ? acc : sneg);
  }
  const int start = Xindex[bt];
  const int len = lens[b];
  const bool valid = (l >= start) && (l < len);
  const int y = Yindex[bt];
  if (l == y) vy_s = v;
  float m = valid ? v : -INFINITY;
  for (int off = 32; off > 0; off >>= 1) m = fmaxf(m, __shfl_xor(m, off, 64));
  const int wid = l >> 6, lane = l & 63;
  if (lane == 0) rbuf[wid] = m;
  __syncthreads();
  const float mx = fmaxf(fmaxf(rbuf[0], rbuf[1]), fmaxf(rbuf[2], rbuf[3]));
  float e = valid ? __expf(v - mx) : 0.0f;
  for (int off = 32; off > 0; off >>= 1) e += __shfl_xor(e, off, 64);
  if (lane == 0) sbuf[wid] = e;
  __syncthreads();
  if (l == 0) {
    const float sum = sbuf[0] + sbuf[1] + sbuf[2] + sbuf[3];
    atomicAdd(out, (mx + __logf(sum) - vy_s) * (1.0f / (B_ * T_)));
  }
}

extern "C" void kernel_launch(void* const* d_in, const int* in_sizes, int n_in,
                              void* d_out, int out_size, void* d_ws, size_t ws_size,
                              hipStream_t stream) {
  (void)in_sizes; (void)n_in; (void)out_size; (void)ws_size;
  const int*   Xin    = (const int*)d_in[0];
  const int*   Xindex = (const int*)d_in[1];
  const int*   Yindex = (const int*)d_in[2];
  const int*   lens   = (const int*)d_in[3];
  const float* emb    = (const float*)d_in[4];
  const float* Wih_e  = (const float*)d_in[5];
  const float* Whh_e  = (const float*)d_in[6];
  const float* bih_e  = (const float*)d_in[7];
  const float* bhh_e  = (const float*)d_in[8];
  const float* Wih_d  = (const float*)d_in[9];
  const float* Whh_d  = (const float*)d_in[10];
  const float* bih_d  = (const float*)d_in[11];
  const float* bhh_d  = (const float*)d_in[12];
  const float* W1     = (const float*)d_in[13];
  const float* W2     = (const float*)d_in[14];
  const float* Vv     = (const float*)d_in[15];

  char* p = (char*)d_ws;
  auto take = [&](size_t bytes) { void* q = (void*)p; p += (bytes + 255) & ~(size_t)255; return q; };
  uint32_t* wT2_e = (uint32_t*)take((size_t)98304 * 4);
  uint32_t* wT2_d = (uint32_t*)take((size_t)98304 * 4);
  float* xg_e  = (float*)take((size_t)8192 * 768 * 4);
  float* xg_d  = (float*)take((size_t)1024 * 768 * 4);
  float* hn    = (float*)take((size_t)8192 * 256 * 4);
  float* hend  = (float*)take((size_t)8192 * 4);
  float* hl_d  = (float*)take((size_t)8192 * 4);
  float* doutb = (float*)take((size_t)1024 * 256 * 4);
  float* WEt   = (float*)take((size_t)8192 * 256 * 4);
  float* WDb   = (float*)take((size_t)1024 * 256 * 4);
  int*   dtok  = (int*)take((size_t)1024 * 4);

  hipMemsetAsync(d_out, 0, sizeof(float), stream);

  hipLaunchKernelGGL(pack_whh, dim3(384), dim3(256), 0, stream, Whh_e, wT2_e);
  hipLaunchKernelGGL(pack_whh, dim3(384), dim3(256), 0, stream, Whh_d, wT2_d);
  hipLaunchKernelGGL(gather_dtok, dim3(4), dim3(256), 0, stream, Xin, Xindex, dtok);

  // xg_e = emb[Xin] @ Wih_e^T + bih_e   [8192 x 768], K=300
  hipLaunchKernelGGL((gemm_awt<true, false, true>), dim3(128, 12), dim3(256), 0, stream,
                     emb, Xin, Wih_e, bih_e, xg_e, 8192, 768, 300);
  // xg_d = emb[dtok] @ Wih_d^T + bih_d  [1024 x 768], K=300
  hipLaunchKernelGGL((gemm_awt<true, false, true>), dim3(16, 12), dim3(256), 0, stream,
                     emb, dtok, Wih_d, bih_d, xg_d, 1024, 768, 300);

  // encoder GRU (h0 = 0), outputs hn [B,L,H] and hend [B,H]
  hipLaunchKernelGGL(gru_seq, dim3(32), dim3(1024), 0, stream,
                     xg_e, wT2_e, bhh_e, (const float*)nullptr, hn, hend, L_);
  // decoder GRU (h0 = hend), outputs doutb [B,T,H]
  hipLaunchKernelGGL(gru_seq, dim3(32), dim3(1024), 0, stream,
                     xg_d, wT2_d, bhh_d, hend, doutb, hl_d, T_);

  // WEt[b][k][l] = sum_h hn[b,l,h] * W1[k,h]   (transposed store)
  hipLaunchKernelGGL((gemm_awt<false, true, false>), dim3(128, 4), dim3(256), 0, stream,
                     hn, (const int*)nullptr, W1, (const float*)nullptr, WEt, 8192, 256, 256);
  // WD[b,t,k] = sum_h doutb[b,t,h] * W2[k,h]
  hipLaunchKernelGGL((gemm_awt<false, false, false>), dim3(16, 4), dim3(256), 0, stream,
                     doutb, (const int*)nullptr, W2, (const float*)nullptr, WDb, 1024, 256, 256);

  // fused pointer layer + loss
  hipLaunchKernelGGL(pointer_loss, dim3(T_, B_), dim3(256), 0, stream,
                     WEt, WDb, Vv, Xindex, Yindex, lens, (float*)d_out);
}

// Round 6
// 475.514 us; speedup vs baseline: 2.0124x; 1.0739x over previous
//
#include <hip/hip_runtime.h>
#include <hip/hip_bf16.h>
#include <stdint.h>

#define B_  32
#define L_  256
#define T_  32
#define D_  300
#define H_  256
#define G3  768   // 3*H

typedef _Float16 half2_t __attribute__((ext_vector_type(2)));

__device__ __forceinline__ float fdot2(uint32_t w, uint32_t h, float acc) {
#if defined(__has_builtin) && __has_builtin(__builtin_amdgcn_fdot2)
  return __builtin_amdgcn_fdot2(__builtin_bit_cast(half2_t, w),
                                __builtin_bit_cast(half2_t, h), acc, false);
#else
  half2_t a = __builtin_bit_cast(half2_t, w);
  half2_t b = __builtin_bit_cast(half2_t, h);
  return acc + (float)a[0] * (float)b[0] + (float)a[1] * (float)b[1];
#endif
}

__device__ __forceinline__ uint32_t pack2(float x, float y) {
  half2_t h;
  h[0] = (_Float16)x;
  h[1] = (_Float16)y;
  return __builtin_bit_cast(uint32_t, h);
}

__device__ __forceinline__ float rcp_f(float x) { return __builtin_amdgcn_rcpf(x); }
__device__ __forceinline__ float sigmoid_f(float x) { return rcp_f(1.0f + __expf(-x)); }
__device__ __forceinline__ float tanh_f(float x) {
  float e2 = __expf(2.0f * x);
  return 1.0f - 2.0f * rcp_f(e2 + 1.0f);
}

// ---- pack Whh [768][256] f32 -> wT2 [128][768] f16x2 (pairs along K) ----
__global__ void pack_whh(const float* __restrict__ Whh, uint32_t* __restrict__ wT2) {
  const int idx = blockIdx.x * 256 + threadIdx.x;   // 0..98303
  const int row = idx % G3;
  const int kk  = idx / G3;
  wT2[idx] = pack2(Whh[row * H_ + 2 * kk], Whh[row * H_ + 2 * kk + 1]);
}

// ---- bsum = bih + bhh for gates r,z; bih only for gate n (bhh_n is inside r*(.)) ----
__global__ void bias_combine(const float* __restrict__ bih, const float* __restrict__ bhh,
                             float* __restrict__ bsum) {
  const int i = blockIdx.x * 256 + threadIdx.x;   // 0..767
  float v = bih[i];
  if (i < 2 * H_) v += bhh[i];
  bsum[i] = v;
}

// ---- dtok[i] = Xin[b*L + Xindex[i]] ----
__global__ void gather_dtok(const int* __restrict__ Xin, const int* __restrict__ Xindex,
                            int* __restrict__ dtok) {
  const int i = blockIdx.x * 256 + threadIdx.x;   // 0..1023
  const int b = i >> 5;                           // /T_
  dtok[i] = Xin[b * L_ + Xindex[i]];
}

// ---- generic C = A @ W^T (+bias), A rows optionally gathered; out optionally
//      stored transposed per 256-row batch: C[b][n][l], m = b*256+l ----
template<bool GATHER, bool TRANSP, bool BIAS>
__global__ __launch_bounds__(256)
void gemm_awt(const float* __restrict__ A, const int* __restrict__ rowidx,
              const float* __restrict__ W, const float* __restrict__ bias,
              float* __restrict__ C, int M, int N, int K) {
  __shared__ float As[16][68];
  __shared__ float Ws[16][68];
  const int tid = threadIdx.x;
  const int bm = blockIdx.x, bn = blockIdx.y;
  const int ty = tid >> 4, tx = tid & 15;
  const int r  = tid >> 2;
  const int c4 = (tid & 3) << 2;
  const long arow = (long)bm * 64 + r;
  const float* Arow = GATHER ? (A + (long)rowidx[arow] * K) : (A + arow * (long)K);
  const float* Wrow = W + ((long)bn * 64 + r) * K;
  float acc[4][4] = {};
  for (int k0 = 0; k0 < K; k0 += 16) {
    float4 av, wv;
    if (k0 + c4 + 3 < K) {
      av = *(const float4*)(Arow + k0 + c4);
      wv = *(const float4*)(Wrow + k0 + c4);
    } else {
      float ta[4] = {0, 0, 0, 0}, tw[4] = {0, 0, 0, 0};
      for (int u = 0; u < 4; ++u)
        if (k0 + c4 + u < K) { ta[u] = Arow[k0 + c4 + u]; tw[u] = Wrow[k0 + c4 + u]; }
      av.x = ta[0]; av.y = ta[1]; av.z = ta[2]; av.w = ta[3];
      wv.x = tw[0]; wv.y = tw[1]; wv.z = tw[2]; wv.w = tw[3];
    }
    __syncthreads();
    As[c4 + 0][r] = av.x; As[c4 + 1][r] = av.y; As[c4 + 2][r] = av.z; As[c4 + 3][r] = av.w;
    Ws[c4 + 0][r] = wv.x; Ws[c4 + 1][r] = wv.y; Ws[c4 + 2][r] = wv.z; Ws[c4 + 3][r] = wv.w;
    __syncthreads();
#pragma unroll
    for (int k = 0; k < 16; ++k) {
      const float4 a4 = *(const float4*)&As[k][ty << 2];
      const float4 b4 = *(const float4*)&Ws[k][tx << 2];
      acc[0][0] = fmaf(a4.x, b4.x, acc[0][0]);
      acc[0][1] = fmaf(a4.x, b4.y, acc[0][1]);
      acc[0][2] = fmaf(a4.x, b4.z, acc[0][2]);
      acc[0][3] = fmaf(a4.x, b4.w, acc[0][3]);
      acc[1][0] = fmaf(a4.y, b4.x, acc[1][0]);
      acc[1][1] = fmaf(a4.y, b4.y, acc[1][1]);
      acc[1][2] = fmaf(a4.y, b4.z, acc[1][2]);
      acc[1][3] = fmaf(a4.y, b4.w, acc[1][3]);
      acc[2][0] = fmaf(a4.z, b4.x, acc[2][0]);
      acc[2][1] = fmaf(a4.z, b4.y, acc[2][1]);
      acc[2][2] = fmaf(a4.z, b4.z, acc[2][2]);
      acc[2][3] = fmaf(a4.z, b4.w, acc[2][3]);
      acc[3][0] = fmaf(a4.w, b4.x, acc[3][0]);
      acc[3][1] = fmaf(a4.w, b4.y, acc[3][1]);
      acc[3][2] = fmaf(a4.w, b4.z, acc[3][2]);
      acc[3][3] = fmaf(a4.w, b4.w, acc[3][3]);
    }
  }
#pragma unroll
  for (int i = 0; i < 4; ++i) {
    const int m = bm * 64 + (ty << 2) + i;
#pragma unroll
    for (int j = 0; j < 4; ++j) {
      const int n = bn * 64 + (tx << 2) + j;
      float v = acc[i][j];
      if (BIAS) v += bias[n];
      if (TRANSP) C[(((long)(m >> 8) * N + n) << 8) + (m & 255)] = v;
      else        C[(long)m * N + n] = v;
    }
  }
}

// ============ sequential GRU, 1024 threads, K split 4-way ============
// tid = q*256 + j. Thread owns rows {j, H+j, 2H+j}, K-pairs [q*32, q*32+32)
// = 96 weight dwords. __launch_bounds__(1024, 4) pins exactly 1 block/CU
// (4 waves/EU) -> 128-VGPR budget; in-loop liveness ~126 so weights stay
// resident (r5 failure: default target was 2 blocks/CU -> 64 VGPR -> weights
// streamed from L2 at ~132 B/cy = the 2900 cy/step bottleneck).
// Gate biases bhh_r,bhh_z folded into xg; bhh_n kept (inside r*(.)).

__device__ __forceinline__ uint4 ld4w(const uint32_t* __restrict__ b, int off, int c) {
  uint4 v;
  v.x = b[(4 * c + 0) * G3 + off];
  v.y = b[(4 * c + 1) * G3 + off];
  v.z = b[(4 * c + 2) * G3 + off];
  v.w = b[(4 * c + 3) * G3 + off];
  return v;
}

#define WDECL8(p) uint4 p##0, p##1, p##2, p##3, p##4, p##5, p##6, p##7
#define WLOAD8(p, base, off) \
  p##0 = ld4w(base, off, 0); p##1 = ld4w(base, off, 1); \
  p##2 = ld4w(base, off, 2); p##3 = ld4w(base, off, 3); \
  p##4 = ld4w(base, off, 4); p##5 = ld4w(base, off, 5); \
  p##6 = ld4w(base, off, 6); p##7 = ld4w(base, off, 7)
#define PIN4(v) asm volatile("" : "+v"(v.x), "+v"(v.y), "+v"(v.z), "+v"(v.w))
#define WPIN8(p) \
  PIN4(p##0); PIN4(p##1); PIN4(p##2); PIN4(p##3); \
  PIN4(p##4); PIN4(p##5); PIN4(p##6); PIN4(p##7)

#define STEP_I(i) { \
  const uint4 hp = hp8[i]; \
  ar = fdot2(wr##i.x, hp.x, ar); az = fdot2(wz##i.x, hp.x, az); an = fdot2(wn##i.x, hp.x, an); \
  ar = fdot2(wr##i.y, hp.y, ar); az = fdot2(wz##i.y, hp.y, az); an = fdot2(wn##i.y, hp.y, an); \
  ar = fdot2(wr##i.z, hp.z, ar); az = fdot2(wz##i.z, hp.z, az); an = fdot2(wn##i.z, hp.z, an); \
  ar = fdot2(wr##i.w, hp.w, ar); az = fdot2(wz##i.w, hp.w, az); an = fdot2(wn##i.w, hp.w, an); }

__global__ __launch_bounds__(1024, 4)
void gru_seq(const float* __restrict__ xg, const uint32_t* __restrict__ wT2,
             const float* __restrict__ bhh, const float* __restrict__ h0,
             float* __restrict__ hout, float* __restrict__ hlast, int S) {
  const int b = blockIdx.x;
  const int tid = threadIdx.x;
  const int j = tid & 255;
  const int q = tid >> 8;
  const uint32_t* wbase = wT2 + (size_t)q * 32 * G3;  // kk base = q*32 pairs
  WDECL8(wr); WDECL8(wz); WDECL8(wn);
  WLOAD8(wr, wbase, j);
  WLOAD8(wz, wbase, H_ + j);
  WLOAD8(wn, wbase, 2 * H_ + j);
  WPIN8(wr); WPIN8(wz); WPIN8(wn);
  __shared__ __align__(16) uint32_t h2[H_ / 2];
  __shared__ float part[3][4][H_];   // [gate][q][j]; q=0 slice unused
  float bhn = 0.0f, h = 0.0f;
  const float* xp = xg + (long)b * S * G3;
  float* hp_out = hout + (long)b * S * H_;
  if (q == 0) {
    bhn = bhh[2 * H_ + j];
    h = h0 ? h0[b * H_ + j] : 0.0f;
    ((_Float16*)h2)[j] = (_Float16)h;
  }
  __syncthreads();
  for (int t = 0; t < S; ++t) {
    float xr = 0.0f, xz = 0.0f, xn = 0.0f;
    if (q == 0) { xr = xp[j]; xz = xp[H_ + j]; xn = xp[2 * H_ + j]; }
    float ar = 0.0f, az = 0.0f, an = 0.0f;
    const uint4* hp8 = (const uint4*)h2 + q * 8;
    STEP_I(0) STEP_I(1) STEP_I(2) STEP_I(3)
    __builtin_amdgcn_sched_barrier(0);   // split region: cap hp liveness at 4 uint4
    STEP_I(4) STEP_I(5) STEP_I(6) STEP_I(7)
    if (q) { part[0][q][j] = ar; part[1][q][j] = az; part[2][q][j] = an; }
    __syncthreads();
    if (q == 0) {
      ar += part[0][1][j] + part[0][2][j] + part[0][3][j];
      az += part[1][1][j] + part[1][2][j] + part[1][3][j];
      an += part[2][1][j] + part[2][2][j] + part[2][3][j];
      const float r = sigmoid_f(xr + ar);        // xr includes bih_r + bhh_r
      const float z = sigmoid_f(xz + az);        // xz includes bih_z + bhh_z
      const float n = tanh_f(xn + r * (an + bhn));
      h = (1.0f - z) * n + z * h;
      hp_out[j] = h;
      ((_Float16*)h2)[j] = (_Float16)h;
    }
    xp += G3;
    hp_out += H_;
    __syncthreads();
  }
  if (q == 0 && hlast) hlast[b * H_ + j] = h;
}

// ---- fused pointer layer + masked log-softmax + loss accumulation ----
// grid (T, B), 256 threads = one per l. WEt is [b][h][l] (transposed).
__global__ __launch_bounds__(256)
void pointer_loss(const float* __restrict__ WEt, const float* __restrict__ WD,
                  const float* __restrict__ Vv,
                  const int* __restrict__ Xindex, const int* __restrict__ Yindex,
                  const int* __restrict__ lens, float* __restrict__ out) {
  const int t = blockIdx.x, b = blockIdx.y;
  const int l = threadIdx.x;
  __shared__ float wd_s[H_], vv_s[H_];
  __shared__ float rbuf[4], sbuf[4], vy_s;
  const int bt = b * T_ + t;
  wd_s[l] = WD[(long)bt * H_ + l];
  vv_s[l] = Vv[l] * 1.0507009873554805f;   // fold selu scale of inner selu into Vv
  __syncthreads();
  const float* wet = WEt + (long)b * H_ * L_;
  const float alpha = 1.6732632423543772f;
  float acc = 0.0f;
#pragma unroll 4
  for (int hh = 0; hh < H_; ++hh) {
    const float xsum = wet[hh * L_ + l] + wd_s[hh];
    const float sneg = alpha * (__expf(xsum) - 1.0f);
    const float s = xsum > 0.0f ? xsum : sneg;
    acc = fmaf(s, vv_s[hh], acc);
  }
  float v;
  {
    const float sneg = alpha * (__expf(acc) - 1.0f);
    v = 1.0507009873554805f * (acc > 0.0f ? acc : sneg);
  }
  const int start = Xindex[bt];
  const int len = lens[b];
  const bool valid = (l >= start) && (l < len);
  const int y = Yindex[bt];
  if (l == y) vy_s = v;
  float m = valid ? v : -INFINITY;
  for (int off = 32; off > 0; off >>= 1) m = fmaxf(m, __shfl_xor(m, off, 64));
  const int wid = l >> 6, lane = l & 63;
  if (lane == 0) rbuf[wid] = m;
  __syncthreads();
  const float mx = fmaxf(fmaxf(rbuf[0], rbuf[1]), fmaxf(rbuf[2], rbuf[3]));
  float e = valid ? __expf(v - mx) : 0.0f;
  for (int off = 32; off > 0; off >>= 1) e += __shfl_xor(e, off, 64);
  if (lane == 0) sbuf[wid] = e;
  __syncthreads();
  if (l == 0) {
    const float sum = sbuf[0] + sbuf[1] + sbuf[2] + sbuf[3];
    atomicAdd(out, (mx + __logf(sum) - vy_s) * (1.0f / (B_ * T_)));
  }
}

extern "C" void kernel_launch(void* const* d_in, const int* in_sizes, int n_in,
                              void* d_out, int out_size, void* d_ws, size_t ws_size,
                              hipStream_t stream) {
  (void)in_sizes; (void)n_in; (void)out_size; (void)ws_size;
  const int*   Xin    = (const int*)d_in[0];
  const int*   Xindex = (const int*)d_in[1];
  const int*   Yindex = (const int*)d_in[2];
  const int*   lens   = (const int*)d_in[3];
  const float* emb    = (const float*)d_in[4];
  const float* Wih_e  = (const float*)d_in[5];
  const float* Whh_e  = (const float*)d_in[6];
  const float* bih_e  = (const float*)d_in[7];
  const float* bhh_e  = (const float*)d_in[8];
  const float* Wih_d  = (const float*)d_in[9];
  const float* Whh_d  = (const float*)d_in[10];
  const float* bih_d  = (const float*)d_in[11];
  const float* bhh_d  = (const float*)d_in[12];
  const float* W1     = (const float*)d_in[13];
  const float* W2     = (const float*)d_in[14];
  const float* Vv     = (const float*)d_in[15];

  char* p = (char*)d_ws;
  auto take = [&](size_t bytes) { void* q = (void*)p; p += (bytes + 255) & ~(size_t)255; return q; };
  uint32_t* wT2_e = (uint32_t*)take((size_t)98304 * 4);
  uint32_t* wT2_d = (uint32_t*)take((size_t)98304 * 4);
  float* xg_e  = (float*)take((size_t)8192 * 768 * 4);
  float* xg_d  = (float*)take((size_t)1024 * 768 * 4);
  float* hn    = (float*)take((size_t)8192 * 256 * 4);
  float* hend  = (float*)take((size_t)8192 * 4);
  float* hl_d  = (float*)take((size_t)8192 * 4);
  float* doutb = (float*)take((size_t)1024 * 256 * 4);
  float* WEt   = (float*)take((size_t)8192 * 256 * 4);
  float* WDb   = (float*)take((size_t)1024 * 256 * 4);
  int*   dtok  = (int*)take((size_t)1024 * 4);
  float* bsum_e = (float*)take((size_t)768 * 4);
  float* bsum_d = (float*)take((size_t)768 * 4);

  hipMemsetAsync(d_out, 0, sizeof(float), stream);

  hipLaunchKernelGGL(pack_whh, dim3(384), dim3(256), 0, stream, Whh_e, wT2_e);
  hipLaunchKernelGGL(pack_whh, dim3(384), dim3(256), 0, stream, Whh_d, wT2_d);
  hipLaunchKernelGGL(bias_combine, dim3(3), dim3(256), 0, stream, bih_e, bhh_e, bsum_e);
  hipLaunchKernelGGL(bias_combine, dim3(3), dim3(256), 0, stream, bih_d, bhh_d, bsum_d);
  hipLaunchKernelGGL(gather_dtok, dim3(4), dim3(256), 0, stream, Xin, Xindex, dtok);

  // xg_e = emb[Xin] @ Wih_e^T + (bih_e + bhh_e|rz)   [8192 x 768], K=300
  hipLaunchKernelGGL((gemm_awt<true, false, true>), dim3(128, 12), dim3(256), 0, stream,
                     emb, Xin, Wih_e, bsum_e, xg_e, 8192, 768, 300);
  // xg_d = emb[dtok] @ Wih_d^T + (bih_d + bhh_d|rz)  [1024 x 768], K=300
  hipLaunchKernelGGL((gemm_awt<true, false, true>), dim3(16, 12), dim3(256), 0, stream,
                     emb, dtok, Wih_d, bsum_d, xg_d, 1024, 768, 300);

  // encoder GRU (h0 = 0), outputs hn [B,L,H] and hend [B,H]
  hipLaunchKernelGGL(gru_seq, dim3(32), dim3(1024), 0, stream,
                     xg_e, wT2_e, bhh_e, (const float*)nullptr, hn, hend, L_);
  // decoder GRU (h0 = hend), outputs doutb [B,T,H]
  hipLaunchKernelGGL(gru_seq, dim3(32), dim3(1024), 0, stream,
                     xg_d, wT2_d, bhh_d, hend, doutb, hl_d, T_);

  // WEt[b][k][l] = sum_h hn[b,l,h] * W1[k,h]   (transposed store)
  hipLaunchKernelGGL((gemm_awt<false, true, false>), dim3(128, 4), dim3(256), 0, stream,
                     hn, (const int*)nullptr, W1, (const float*)nullptr, WEt, 8192, 256, 256);
  // WD[b,t,k] = sum_h doutb[b,t,h] * W2[k,h]
  hipLaunchKernelGGL((gemm_awt<false, false, false>), dim3(16, 4), dim3(256), 0, stream,
                     doutb, (const int*)nullptr, W2, (const float*)nullptr, WDb, 1024, 256, 256);

  // fused pointer layer + loss
  hipLaunchKernelGGL(pointer_loss, dim3(T_, B_), dim3(256), 0, stream,
                     WEt, WDb, Vv, Xindex, Yindex, lens, (float*)d_out);
}